// Round 2
// baseline (129.634 us; speedup 1.0000x reference)
//
#include <hip/hip_runtime.h>
#include <math.h>

#define N_OCT 16
#define NPAIR 8
#define NS    32768
#define TPB   1024
#define SPT   (NS / TPB)   // 32 samples per thread
#define N_BE  512          // B*E = 8*64

typedef float v2f __attribute__((ext_vector_type(2)));

static __device__ __forceinline__ v2f fma2(v2f a, v2f b, v2f c) {
    return __builtin_elementwise_fma(a, b, c);
}

// One block per (b,e) row; thread t owns samples s = k*TPB + t (strided,
// conflict-free LDS + coalesced global). Per-octave sinusoid advanced with a
// Chebyshev 2-term recurrence x_{n+1} = c2*x_n - x_{n-1}, c2 = 2cos(TPB*f0s)
// held as a DOUBLE-FLOAT pair (c2h + c2l) so the effective frequency has
// ~2^-48 relative error regardless of how close TPB*f0s mod 2pi lands to
// 0/pi (the single-float c2 form is ill-conditioned there). Octaves are
// paired into float2 so clang can emit v_pk_fma_f32 (packed fp32, 2x rate).
__global__ __launch_bounds__(TPB)
void f0res_kernel(const float* __restrict__ f0_in,
                  const float* __restrict__ dc_in,
                  const float* __restrict__ fs_in,
                  float* __restrict__ out)
{
    extern __shared__ float smem[];          // NS floats = 128 KiB dynamic LDS
    __shared__ float wmax[TPB / 64];

    const int be = blockIdx.x;
    const int t  = threadIdx.x;

    const float f0a = fabsf(f0_in[be]);
    const float dc  = dc_in[be];
    const float fs  = fs_in[be];

    const float MINF = (float)(20.0 / 11025.0);
    const float FRNG = (float)(3000.0 / 11025.0 - 20.0 / 11025.0);

    // double sigmoid (reference applies sigmoid twice), decay ladder
    const float s1    = 1.0f / (1.0f + __expf(-dc));
    const float dv    = 1.0f / (1.0f + __expf(-s1));
    const float decay = 0.01f + dv * 0.9801f;          // (1-0.01)*0.99
    const float logd  = __logf(decay + 1e-12f);
    const float f0r   = (MINF + f0a * FRNG) * 3.14159274101257324f;

    // Paired per-octave state: component x = octave 2j, y = octave 2j+1
    v2f xp[NPAIR], xc[NPAIR], c2h[NPAIR], c2l[NPAIR], amp2[NPAIR];

    float cl = 0.f, cf = 0.f;
    const double inv2pi = 0.15915494309189535;
    #pragma unroll
    for (int o = 0; o < N_OCT; ++o) {
        cl += logd;                                    // float32 cumsum like ref
        cf += fs;
        float ed  = __expf(cl);                        // decay^(o+1)
        float f0s = f0r * cf;                          // rad/sample, float32
        float a   = ed;
        if (!(f0s < 1.0f)) { a = 0.0f; f0s = 0.0f; }   // nyquist cutoff

        double r  = (double)f0s * inv2pi;              // revolutions/sample
        double p0 = r * (double)(t + 1);               // phase at sample s=t
        p0 -= floor(p0);
        double pm = r * (double)(t + 1 - TPB);         // phase at s = t-TPB
        pm -= floor(pm);
        float xcur  = __builtin_amdgcn_sinf((float)p0);
        float xprev = __builtin_amdgcn_sinf((float)pm);

        // c2 = 2*cos(TPB * f0s), double-float split
        double drev = r * (double)TPB;
        drev -= floor(drev);
        double c2d = 2.0 * cos(drev * 6.283185307179586);
        float  ch  = (float)c2d;
        float  clo = (float)(c2d - (double)ch);

        const int j = o >> 1, q = o & 1;
        if (q == 0) {
            xc[j].x = xcur;  xp[j].x = xprev;
            c2h[j].x = ch;   c2l[j].x = clo;  amp2[j].x = a;
        } else {
            xc[j].y = xcur;  xp[j].y = xprev;
            c2h[j].y = ch;   c2l[j].y = clo;  amp2[j].y = a;
        }
    }

    float lmax = 0.0f;
    #pragma unroll 4
    for (int k = 0; k < SPT; ++k) {
        v2f acc2 = (v2f)(0.0f);
        #pragma unroll
        for (int j = 0; j < NPAIR; ++j) {
            acc2 = fma2(amp2[j], xc[j], acc2);
            v2f xn = fma2(c2h[j], xc[j], fma2(c2l[j], xc[j], -xp[j]));
            xp[j] = xc[j];
            xc[j] = xn;
        }
        float acc = acc2.x + acc2.y;
        smem[k * TPB + t] = acc;                       // coalesced, conflict-free
        lmax = fmaxf(lmax, fabsf(acc));
    }

    // block max reduction: wave shuffle then tiny LDS
    #pragma unroll
    for (int off = 32; off > 0; off >>= 1)
        lmax = fmaxf(lmax, __shfl_down(lmax, off, 64));
    if ((t & 63) == 0) wmax[t >> 6] = lmax;
    __syncthreads();
    float bmax = wmax[0];
    #pragma unroll
    for (int w = 1; w < TPB / 64; ++w) bmax = fmaxf(bmax, wmax[w]);

    const float norm = 1.0f / (bmax + 1e-8f);
    float4*       out4 = (float4*)(out + (size_t)be * NS);
    const float4* s4   = (const float4*)smem;
    #pragma unroll
    for (int j = 0; j < NS / 4 / TPB; ++j) {           // 8 float4 stores/thread
        int i = j * TPB + t;
        float4 v = s4[i];
        v.x *= norm; v.y *= norm; v.z *= norm; v.w *= norm;
        out4[i] = v;
    }
}

extern "C" void kernel_launch(void* const* d_in, const int* in_sizes, int n_in,
                              void* d_out, int out_size, void* d_ws, size_t ws_size,
                              hipStream_t stream) {
    const float* f0 = (const float*)d_in[0];
    const float* dc = (const float*)d_in[1];
    const float* fs = (const float*)d_in[3];   // d_in[2] is "unused"
    float* out = (float*)d_out;
    hipLaunchKernelGGL(f0res_kernel, dim3(N_BE), dim3(TPB),
                       NS * sizeof(float), stream, f0, dc, fs, out);
}

// Round 3
// 109.648 us; speedup vs baseline: 1.1823x; 1.1823x over previous
//
#include <hip/hip_runtime.h>
#include <hip/hip_fp16.h>
#include <math.h>

#define N_OCT 16
#define NPAIR 8
#define NS    32768
#define TPB   512
#define SPT   (NS / TPB)   // 64 samples per thread
#define N_BE  512          // B*E = 8*64

typedef float v2f __attribute__((ext_vector_type(2)));
typedef _Float16 h4 __attribute__((ext_vector_type(4)));

static __device__ __forceinline__ v2f fma2(v2f a, v2f b, v2f c) {
    return __builtin_elementwise_fma(a, b, c);
}

// One block per (b,e) row; thread t owns samples s = k*TPB + t.
// Per-octave sinusoid advanced with Chebyshev 2-term recurrence
//   x_{n+1} = c2*x_n - x_{n-1},  c2 = 2cos(TPB*f0s)
// with c2 held as a DOUBLE-FLOAT pair (2^-48 effective frequency error —
// the single-float form is ill-conditioned when TPB*f0s mod 2pi ~ 0/pi).
// amp is folded into the oscillator (linear recurrence) -> accumulate is an
// ADD and the amp registers vanish. Octaves paired into float2 for
// v_pk_fma_f32. Staged waveform goes to LDS as fp16 (64 KiB) so TWO blocks
// fit per CU (epilogue write of one block overlaps compute of the other).
// NOTE: __launch_bounds__ 2nd arg = waves/EU. 4 waves/EU -> VGPR cap 128,
// 2 blocks/CU. R1 regression: bare bounds at TPB=1024 capped VGPRs at 64 ->
// 165 MB of scratch-spill HBM traffic. Keep this explicit.
__global__ __launch_bounds__(TPB, 4)
void f0res_kernel(const float* __restrict__ f0_in,
                  const float* __restrict__ dc_in,
                  const float* __restrict__ fs_in,
                  float* __restrict__ out)
{
    extern __shared__ _Float16 smem[];       // NS halves = 64 KiB dynamic LDS
    __shared__ float wmax[TPB / 64];

    const int be = blockIdx.x;
    const int t  = threadIdx.x;

    const float f0a = fabsf(f0_in[be]);
    const float dc  = dc_in[be];
    const float fs  = fs_in[be];

    const float MINF = (float)(20.0 / 11025.0);
    const float FRNG = (float)(3000.0 / 11025.0 - 20.0 / 11025.0);

    // double sigmoid (reference applies sigmoid twice), decay ladder
    const float s1    = 1.0f / (1.0f + __expf(-dc));
    const float dv    = 1.0f / (1.0f + __expf(-s1));
    const float decay = 0.01f + dv * 0.9801f;          // (1-0.01)*0.99
    const float logd  = __logf(decay + 1e-12f);
    const float f0r   = (MINF + f0a * FRNG) * 3.14159274101257324f;

    // Paired per-octave state: component x = octave 2j, y = octave 2j+1
    v2f xp[NPAIR], xc[NPAIR], c2h[NPAIR], c2l[NPAIR];

    float cl = 0.f, cf = 0.f;
    const double inv2pi = 0.15915494309189535;
    #pragma unroll
    for (int o = 0; o < N_OCT; ++o) {
        cl += logd;                                    // float32 cumsum like ref
        cf += fs;
        float ed  = __expf(cl);                        // decay^(o+1)
        float f0s = f0r * cf;                          // rad/sample, float32
        float a   = ed;
        if (!(f0s < 1.0f)) { a = 0.0f; f0s = 0.0f; }   // nyquist cutoff

        double r  = (double)f0s * inv2pi;              // revolutions/sample
        double p0 = r * (double)(t + 1);               // phase at sample s=t
        p0 -= floor(p0);
        double pm = r * (double)(t + 1 - TPB);         // phase at s = t-TPB
        pm -= floor(pm);
        float xcur  = a * __builtin_amdgcn_sinf((float)p0);  // amp folded in
        float xprev = a * __builtin_amdgcn_sinf((float)pm);

        // c2 = 2*cos(TPB * f0s), double-float split
        double drev = r * (double)TPB;
        drev -= floor(drev);
        double c2d = 2.0 * cos(drev * 6.283185307179586);
        float  ch  = (float)c2d;
        float  clo = (float)(c2d - (double)ch);

        const int j = o >> 1;
        if ((o & 1) == 0) {
            xc[j].x = xcur;  xp[j].x = xprev;
            c2h[j].x = ch;   c2l[j].x = clo;
        } else {
            xc[j].y = xcur;  xp[j].y = xprev;
            c2h[j].y = ch;   c2l[j].y = clo;
        }
    }

    float lmax = 0.0f;
    #pragma unroll 4
    for (int k = 0; k < SPT; ++k) {
        v2f acc2 = (v2f)(0.0f);
        #pragma unroll
        for (int j = 0; j < NPAIR; ++j) {
            acc2 += xc[j];                              // amp pre-folded
            v2f xn = fma2(c2h[j], xc[j], fma2(c2l[j], xc[j], -xp[j]));
            xp[j] = xc[j];
            xc[j] = xn;
        }
        float acc = acc2.x + acc2.y;
        smem[k * TPB + t] = (_Float16)acc;             // fp16 stage, coalesced
        lmax = fmaxf(lmax, fabsf(acc));
    }

    // block max reduction: wave shuffle then tiny LDS
    #pragma unroll
    for (int off = 32; off > 0; off >>= 1)
        lmax = fmaxf(lmax, __shfl_down(lmax, off, 64));
    if ((t & 63) == 0) wmax[t >> 6] = lmax;
    __syncthreads();
    float bmax = wmax[0];
    #pragma unroll
    for (int w = 1; w < TPB / 64; ++w) bmax = fmaxf(bmax, wmax[w]);

    const float norm = 1.0f / (bmax + 1e-8f);
    float4* out4 = (float4*)(out + (size_t)be * NS);
    #pragma unroll
    for (int j = 0; j < NS / 4 / TPB; ++j) {           // 16 float4 stores/thread
        int i = j * TPB + t;                           // float4 index
        h4 v = *(const h4*)(smem + 4 * (size_t)i);     // ds_read_b64, 8B aligned
        float4 o;
        o.x = (float)v.x * norm; o.y = (float)v.y * norm;
        o.z = (float)v.z * norm; o.w = (float)v.w * norm;
        out4[i] = o;
    }
}

extern "C" void kernel_launch(void* const* d_in, const int* in_sizes, int n_in,
                              void* d_out, int out_size, void* d_ws, size_t ws_size,
                              hipStream_t stream) {
    const float* f0 = (const float*)d_in[0];
    const float* dc = (const float*)d_in[1];
    const float* fs = (const float*)d_in[3];   // d_in[2] is "unused"
    float* out = (float*)d_out;
    hipLaunchKernelGGL(f0res_kernel, dim3(N_BE), dim3(TPB),
                       NS * sizeof(_Float16), stream, f0, dc, fs, out);
}

// Round 4
// 106.037 us; speedup vs baseline: 1.2225x; 1.0341x over previous
//
#include <hip/hip_runtime.h>
#include <hip/hip_fp16.h>
#include <math.h>

#define N_OCT 16
#define NPAIR 8
#define NS    32768
#define TPB   512
#define SPT   (NS / TPB)   // 64 samples per thread
#define N_BE  512          // B*E = 8*64

typedef float v2f __attribute__((ext_vector_type(2)));
typedef _Float16 h4 __attribute__((ext_vector_type(4)));

static __device__ __forceinline__ v2f fma2(v2f a, v2f b, v2f c) {
    return __builtin_elementwise_fma(a, b, c);
}

static __device__ __forceinline__ float bcast0(float x) {
    return __int_as_float(__builtin_amdgcn_readfirstlane(__float_as_int(x)));
}

// One block per (b,e) row; thread t owns samples s = k*TPB + t.
// Per-octave sinusoid advanced with Chebyshev 2-term recurrence
//   x_{n+1} = c2*x_n - x_{n-1},  c2 = 2cos(TPB*f0s)
// with c2 held as a DOUBLE-FLOAT pair (2^-48 effective frequency error —
// single-float c2 is ill-conditioned when TPB*f0s mod 2pi ~ 0/pi).
// amp folded into the oscillator (linear recurrence). Octaves paired into
// float2 for v_pk_fma_f32. fp16 LDS staging (64 KiB) -> 2 blocks/CU, all
// 512 blocks resident at once.
//
// LAUNCH BOUNDS (measured, this ROCm/gfx950): second arg behaves like
// CUDA blocks/CU, NOT waves/EU: (512,4) capped VGPRs at 64 -> 66 MB spill
// traffic (R2: WRITE 109568 KB, FETCH 21.5 MB). (512,2) -> cap >=128.
// Oscillator state alone is 64 VGPRs; do not lower this.
__global__ __launch_bounds__(TPB, 2)
void f0res_kernel(const float* __restrict__ f0_in,
                  const float* __restrict__ dc_in,
                  const float* __restrict__ fs_in,
                  float* __restrict__ out)
{
    extern __shared__ _Float16 smem[];       // NS halves = 64 KiB dynamic LDS
    __shared__ float wmax[TPB / 64];

    const int be = blockIdx.x;
    const int t  = threadIdx.x;

    const float f0a = bcast0(fabsf(f0_in[be]));
    const float dc  = bcast0(dc_in[be]);
    const float fs  = bcast0(fs_in[be]);

    const float MINF = (float)(20.0 / 11025.0);
    const float FRNG = (float)(3000.0 / 11025.0 - 20.0 / 11025.0);

    // double sigmoid (reference applies sigmoid twice), decay ladder
    const float s1    = 1.0f / (1.0f + __expf(-dc));
    const float dv    = 1.0f / (1.0f + __expf(-s1));
    const float decay = 0.01f + dv * 0.9801f;          // (1-0.01)*0.99
    const float logd  = __logf(decay + 1e-12f);
    const float f0r   = (MINF + f0a * FRNG) * 3.14159274101257324f;

    // Paired per-octave state: component x = octave 2j, y = octave 2j+1
    v2f xp[NPAIR], xc[NPAIR], c2h[NPAIR], c2l[NPAIR];

    float cl = 0.f, cf = 0.f;
    const double inv2pi = 0.15915494309189535;
    #pragma unroll
    for (int o = 0; o < N_OCT; ++o) {
        cl += logd;                                    // float32 cumsum like ref
        cf += fs;
        float ed  = __expf(cl);                        // decay^(o+1)
        float f0s = f0r * cf;                          // rad/sample, float32
        float a   = ed;
        if (!(f0s < 1.0f)) { a = 0.0f; f0s = 0.0f; }   // nyquist cutoff

        double r  = (double)f0s * inv2pi;              // revolutions/sample
        double p0 = r * (double)(t + 1);               // phase at sample s=t
        p0 -= floor(p0);
        double pm = r * (double)(t + 1 - TPB);         // phase at s = t-TPB
        pm -= floor(pm);
        float xcur  = a * __builtin_amdgcn_sinf((float)p0);  // amp folded in
        float xprev = a * __builtin_amdgcn_sinf((float)pm);

        // c2 = 2*cos(TPB * f0s), double-float split (block-uniform values)
        double drev = r * (double)TPB;
        drev -= floor(drev);
        double c2d = 2.0 * cos(drev * 6.283185307179586);
        float  ch  = bcast0((float)c2d);
        float  clo = bcast0((float)(c2d - (double)ch));

        const int j = o >> 1;
        if ((o & 1) == 0) {
            xc[j].x = xcur;  xp[j].x = xprev;
            c2h[j].x = ch;   c2l[j].x = clo;
        } else {
            xc[j].y = xcur;  xp[j].y = xprev;
            c2h[j].y = ch;   c2l[j].y = clo;
        }
    }

    float lmax = 0.0f;
    #pragma unroll 4
    for (int k = 0; k < SPT; ++k) {
        v2f acc2 = (v2f)(0.0f);
        #pragma unroll
        for (int j = 0; j < NPAIR; ++j) {
            acc2 += xc[j];                              // amp pre-folded
            v2f xn = fma2(c2h[j], xc[j], fma2(c2l[j], xc[j], -xp[j]));
            xp[j] = xc[j];
            xc[j] = xn;
        }
        float acc = acc2.x + acc2.y;
        smem[k * TPB + t] = (_Float16)acc;             // fp16 stage, coalesced
        lmax = fmaxf(lmax, fabsf(acc));
    }

    // block max reduction: wave shuffle then tiny LDS
    #pragma unroll
    for (int off = 32; off > 0; off >>= 1)
        lmax = fmaxf(lmax, __shfl_down(lmax, off, 64));
    if ((t & 63) == 0) wmax[t >> 6] = lmax;
    __syncthreads();
    float bmax = wmax[0];
    #pragma unroll
    for (int w = 1; w < TPB / 64; ++w) bmax = fmaxf(bmax, wmax[w]);

    const float norm = 1.0f / (bmax + 1e-8f);
    float4* out4 = (float4*)(out + (size_t)be * NS);
    #pragma unroll
    for (int j = 0; j < NS / 4 / TPB; ++j) {           // 16 float4 stores/thread
        int i = j * TPB + t;                           // float4 index
        h4 v = *(const h4*)(smem + 4 * (size_t)i);     // ds_read_b64, 8B aligned
        float4 o;
        o.x = (float)v.x * norm; o.y = (float)v.y * norm;
        o.z = (float)v.z * norm; o.w = (float)v.w * norm;
        out4[i] = o;
    }
}

extern "C" void kernel_launch(void* const* d_in, const int* in_sizes, int n_in,
                              void* d_out, int out_size, void* d_ws, size_t ws_size,
                              hipStream_t stream) {
    const float* f0 = (const float*)d_in[0];
    const float* dc = (const float*)d_in[1];
    const float* fs = (const float*)d_in[3];   // d_in[2] is "unused"
    float* out = (float*)d_out;
    hipLaunchKernelGGL(f0res_kernel, dim3(N_BE), dim3(TPB),
                       NS * sizeof(_Float16), stream, f0, dc, fs, out);
}

// Round 5
// 99.678 us; speedup vs baseline: 1.3005x; 1.0638x over previous
//
#include <hip/hip_runtime.h>
#include <hip/hip_fp16.h>
#include <math.h>

#define N_OCT 16
#define NPAIR 8
#define NS    32768
#define TPB   512
#define SPT   (NS / TPB)   // 64 samples per thread
#define N_BE  512          // B*E = 8*64

typedef float v2f __attribute__((ext_vector_type(2)));
typedef _Float16 h4 __attribute__((ext_vector_type(4)));

static __device__ __forceinline__ v2f fma2(v2f a, v2f b, v2f c) {
    return __builtin_elementwise_fma(a, b, c);
}

// d_ws layout (bytes): [0, 64K) r double[8192]; [64K, 96K) c2h float[8192];
// [96K,128K) c2l; [128K,160K) amp. Rewritten by setup kernel EVERY launch
// (harness poisons d_ws with 0xAA before each timed call).
#define WS_R(ws)    ((double*)(ws))
#define WS_C2H(ws)  ((float*)((char*)(ws) + 65536))
#define WS_C2L(ws)  ((float*)((char*)(ws) + 98304))
#define WS_AMP(ws)  ((float*)((char*)(ws) + 131072))

// Per-(be,octave) block-uniform constants. Hoisted out of the main kernel:
// the 16 double cos() + sigmoid/log/exp chains were paid by EVERY wave
// (R0..R3 all ~42-52us despite 4x main-loop op reduction -> fixed prologue
// cost dominated), and their FP64 temporaries set the VGPR high-water mark.
__global__ __launch_bounds__(256)
void f0res_setup(const float* __restrict__ f0_in,
                 const float* __restrict__ dc_in,
                 const float* __restrict__ fs_in,
                 void* __restrict__ ws)
{
    const int idx = blockIdx.x * 256 + threadIdx.x;   // 8192 = 512 rows x 16 oct
    if (idx >= N_BE * N_OCT) return;
    const int be = idx >> 4, o = idx & 15;

    const float f0a = fabsf(f0_in[be]);
    const float dc  = dc_in[be];
    const float fs  = fs_in[be];

    const float MINF = (float)(20.0 / 11025.0);
    const float FRNG = (float)(3000.0 / 11025.0 - 20.0 / 11025.0);

    // double sigmoid (reference applies sigmoid twice), decay ladder
    const float s1    = 1.0f / (1.0f + __expf(-dc));
    const float dv    = 1.0f / (1.0f + __expf(-s1));
    const float decay = 0.01f + dv * 0.9801f;          // (1-0.01)*0.99
    const float logd  = __logf(decay + 1e-12f);
    const float f0r   = (MINF + f0a * FRNG) * 3.14159274101257324f;

    // sequential float cumsum, bit-matching the reference's jnp.cumsum
    float cl = 0.f, cf = 0.f;
    for (int i = 0; i <= o; ++i) { cl += logd; cf += fs; }
    float ed  = __expf(cl);                            // decay^(o+1)
    float f0s = f0r * cf;                              // rad/sample, float32
    float a   = ed;
    if (!(f0s < 1.0f)) { a = 0.0f; f0s = 0.0f; }       // nyquist cutoff

    const double inv2pi = 0.15915494309189535;
    double r = (double)f0s * inv2pi;                   // revolutions/sample

    // c2 = 2*cos(TPB*f0s) as a double-float pair: 2^-48 effective frequency
    // error (single-float c2 is ill-conditioned when TPB*f0s mod 2pi ~ 0/pi)
    double drev = r * (double)TPB;
    drev -= floor(drev);
    double c2d = 2.0 * cos(drev * 6.283185307179586);
    float  ch  = (float)c2d;

    WS_R(ws)[idx]   = r;
    WS_C2H(ws)[idx] = ch;
    WS_C2L(ws)[idx] = (float)(c2d - (double)ch);
    WS_AMP(ws)[idx] = a;
}

// One block per (b,e) row; thread t owns samples s = k*TPB + t.
// Chebyshev 2-term recurrence x_{n+1} = c2*x_n - x_{n-1}, amp folded into
// the oscillator state (linear recurrence). Octaves paired into float2 for
// v_pk_fma_f32. fp16 LDS staging (64 KiB) -> 2 blocks/CU, all 512 blocks
// resident. Uniform per-octave constants come from the d_ws table (s_load).
//
// LAUNCH BOUNDS: (512,1) is the only verified spill-free setting on this
// ROCm (R0: 68 VGPR, WRITE_SIZE exactly 65536 KB). (512,4) gave a 64-VGPR
// cap -> 66 MB of scratch spill (R2). LDS caps residency at 2 blocks/CU
// regardless, so the loose bound costs no occupancy.
__global__ __launch_bounds__(TPB, 1)
void f0res_kernel(const void* __restrict__ ws,
                  float* __restrict__ out)
{
    extern __shared__ _Float16 smem[];       // NS halves = 64 KiB dynamic LDS
    __shared__ float wmax[TPB / 64];

    const int be = blockIdx.x;
    const int t  = threadIdx.x;

    const double* __restrict__ Rtab = WS_R(ws)   + be * N_OCT;
    const float*  __restrict__ CH   = WS_C2H(ws) + be * N_OCT;
    const float*  __restrict__ CLo  = WS_C2L(ws) + be * N_OCT;
    const float*  __restrict__ AMP  = WS_AMP(ws) + be * N_OCT;

    // Paired per-octave state: component x = octave 2j, y = octave 2j+1
    v2f xp[NPAIR], xc[NPAIR], c2h[NPAIR], c2l[NPAIR];

    #pragma unroll
    for (int o = 0; o < N_OCT; ++o) {
        const double r = Rtab[o];                      // uniform -> s_load
        const float  a = AMP[o];

        double p0 = r * (double)(t + 1);               // phase at sample s=t
        p0 -= floor(p0);
        double pm = r * (double)(t + 1 - TPB);         // phase at s = t-TPB
        pm -= floor(pm);
        float xcur  = a * __builtin_amdgcn_sinf((float)p0);  // amp folded in
        float xprev = a * __builtin_amdgcn_sinf((float)pm);

        const int j = o >> 1;
        if ((o & 1) == 0) {
            xc[j].x = xcur;   xp[j].x = xprev;
            c2h[j].x = CH[o]; c2l[j].x = CLo[o];
        } else {
            xc[j].y = xcur;   xp[j].y = xprev;
            c2h[j].y = CH[o]; c2l[j].y = CLo[o];
        }
    }

    float lmax = 0.0f;
    #pragma unroll 4
    for (int k = 0; k < SPT; ++k) {
        v2f acc2 = (v2f)(0.0f);
        #pragma unroll
        for (int j = 0; j < NPAIR; ++j) {
            acc2 += xc[j];                              // amp pre-folded
            v2f xn = fma2(c2h[j], xc[j], fma2(c2l[j], xc[j], -xp[j]));
            xp[j] = xc[j];
            xc[j] = xn;
        }
        float acc = acc2.x + acc2.y;
        smem[k * TPB + t] = (_Float16)acc;             // fp16 stage, coalesced
        lmax = fmaxf(lmax, fabsf(acc));
    }

    // block max reduction: wave shuffle then tiny LDS
    #pragma unroll
    for (int off = 32; off > 0; off >>= 1)
        lmax = fmaxf(lmax, __shfl_down(lmax, off, 64));
    if ((t & 63) == 0) wmax[t >> 6] = lmax;
    __syncthreads();
    float bmax = wmax[0];
    #pragma unroll
    for (int w = 1; w < TPB / 64; ++w) bmax = fmaxf(bmax, wmax[w]);

    const float norm = 1.0f / (bmax + 1e-8f);
    float4* out4 = (float4*)(out + (size_t)be * NS);
    #pragma unroll
    for (int j = 0; j < NS / 4 / TPB; ++j) {           // 16 float4 stores/thread
        int i = j * TPB + t;                           // float4 index
        h4 v = *(const h4*)(smem + 4 * (size_t)i);     // ds_read_b64, 8B aligned
        float4 o;
        o.x = (float)v.x * norm; o.y = (float)v.y * norm;
        o.z = (float)v.z * norm; o.w = (float)v.w * norm;
        out4[i] = o;
    }
}

extern "C" void kernel_launch(void* const* d_in, const int* in_sizes, int n_in,
                              void* d_out, int out_size, void* d_ws, size_t ws_size,
                              hipStream_t stream) {
    const float* f0 = (const float*)d_in[0];
    const float* dc = (const float*)d_in[1];
    const float* fs = (const float*)d_in[3];   // d_in[2] is "unused"
    float* out = (float*)d_out;

    hipLaunchKernelGGL(f0res_setup, dim3((N_BE * N_OCT + 255) / 256), dim3(256),
                       0, stream, f0, dc, fs, d_ws);
    hipLaunchKernelGGL(f0res_kernel, dim3(N_BE), dim3(TPB),
                       NS * sizeof(_Float16), stream, d_ws, out);
}